// Round 2
// baseline (431.113 us; speedup 1.0000x reference)
//
#include <hip/hip_runtime.h>
#include <cstddef>

#define NN   50000
#define KNB  32

// ---------------- compare-exchange helpers ----------------
__device__ __forceinline__ void ce(float& a, float& b) {
  float lo = fminf(a, b);
  float hi = fmaxf(a, b);
  a = lo;
  b = hi;
}

__device__ __forceinline__ void ce2(float2& a, float2& b) {
  float lx = fminf(a.x, b.x), hx = fmaxf(a.x, b.x);
  float ly = fminf(a.y, b.y), hy = fmaxf(a.y, b.y);
  a = make_float2(lx, ly);
  b = make_float2(hx, hy);
}

// Batcher odd-even mergesort, 32 elements, fully unrolled. Only v[15] is
// consumed -> compiler DCEs the dead cone.
__device__ __forceinline__ void sort32(float2 (&v)[32]) {
  #pragma unroll
  for (int p = 1; p < 32; p <<= 1) {
    #pragma unroll
    for (int k = p; k >= 1; k >>= 1) {
      #pragma unroll
      for (int j = k & (p - 1); j + k < 32; j += 2 * k) {
        #pragma unroll
        for (int i = 0; i < k; ++i) {
          if (i + j + k < 32) {
            if ((i + j) / (2 * p) == (i + j + k) / (2 * p)) {
              ce2(v[i + j], v[i + j + k]);
            }
          }
        }
      }
    }
  }
}

// ---------------- GEMM1: C[M,128] = A[M,512] @ B[512,128] + bias ----------
// 256 threads, BM=64, BN=128, TM=4, TN=8 (two contiguous float4 half-panels).
// As stored transposed [BK][BM+4] -> a-frag is one ds_read_b128 (broadcast).
// Bs padded +4 words; staged with consecutive lanes -> consecutive chunks.
__global__ __launch_bounds__(256) void gemm1(const float* __restrict__ A,
                                             const float* __restrict__ B,
                                             const float* __restrict__ bias,
                                             float* __restrict__ C, int M) {
  constexpr int K = 512, BM = 64, BN = 128, BK = 32, TM = 4;
  __shared__ float As[BK][BM + 4];   // transposed A tile
  __shared__ float Bs[BK][BN + 4];
  const int tid  = threadIdx.x;
  const int tx   = tid & 15;         // col group: cols tx*4 and 64+tx*4
  const int ty   = tid >> 4;         // row group 0..15: rows ty*4..ty*4+3
  const int row0 = blockIdx.x * BM;

  float acc[TM][8] = {};

  const int ar     = tid >> 2;         // 0..63 A-stage row
  const int ac     = (tid & 3) * 8;    // k-offset 0,8,16,24
  const int bchunk = (tid & 31) * 4;   // 0..124 (col)
  const int brow0  = tid >> 5;         // 0..7

  for (int k0 = 0; k0 < K; k0 += BK) {
    // stage A (64x32) transposed: 8 floats/thread
    {
      const int grow = row0 + ar;
      float4 t0, t1;
      if (grow < M) {
        const float* p = A + (size_t)grow * K + k0 + ac;
        t0 = *(const float4*)p;
        t1 = *(const float4*)(p + 4);
      } else {
        t0 = t1 = make_float4(0.f, 0.f, 0.f, 0.f);
      }
      As[ac + 0][ar] = t0.x; As[ac + 1][ar] = t0.y;
      As[ac + 2][ar] = t0.z; As[ac + 3][ar] = t0.w;
      As[ac + 4][ar] = t1.x; As[ac + 5][ar] = t1.y;
      As[ac + 6][ar] = t1.z; As[ac + 7][ar] = t1.w;
    }
    // stage B (32x128): 4 rounds, lanes cover contiguous chunks per row
    #pragma unroll
    for (int q = 0; q < 4; ++q) {
      const int br = brow0 + 8 * q;
      *(float4*)&Bs[br][bchunk] =
          *(const float4*)(B + (size_t)(k0 + br) * BN + bchunk);
    }
    __syncthreads();

    #pragma unroll
    for (int kk = 0; kk < BK; ++kk) {
      const float4 a4 = *(const float4*)&As[kk][ty * TM];
      const float4 b0 = *(const float4*)&Bs[kk][tx * 4];
      const float4 b1 = *(const float4*)&Bs[kk][64 + tx * 4];
      const float a[4] = {a4.x, a4.y, a4.z, a4.w};
      const float b[8] = {b0.x, b0.y, b0.z, b0.w, b1.x, b1.y, b1.z, b1.w};
      #pragma unroll
      for (int i = 0; i < TM; ++i)
        #pragma unroll
        for (int j = 0; j < 8; ++j)
          acc[i][j] += a[i] * b[j];
    }
    __syncthreads();
  }

  const float4 u0 = *(const float4*)(bias + tx * 4);
  const float4 u1 = *(const float4*)(bias + 64 + tx * 4);
  #pragma unroll
  for (int i = 0; i < TM; ++i) {
    const int grow = row0 + ty * TM + i;
    if (grow < M) {
      float4 r0 = make_float4(acc[i][0] + u0.x, acc[i][1] + u0.y,
                              acc[i][2] + u0.z, acc[i][3] + u0.w);
      float4 r1 = make_float4(acc[i][4] + u1.x, acc[i][5] + u1.y,
                              acc[i][6] + u1.z, acc[i][7] + u1.w);
      *(float4*)(C + (size_t)grow * BN + tx * 4)      = r0;
      *(float4*)(C + (size_t)grow * BN + 64 + tx * 4) = r1;
    }
  }
}

// ---------------- GEMM2: C[M,64] = A[M,128] @ B[128,64] + bias ------------
// 256 threads, BM=64, BN=64, TM=4, TN=4.
__global__ __launch_bounds__(256) void gemm2(const float* __restrict__ A,
                                             const float* __restrict__ B,
                                             const float* __restrict__ bias,
                                             float* __restrict__ C, int M) {
  constexpr int K = 128, BM = 64, BN = 64, BK = 32, TM = 4;
  __shared__ float As[BK][BM + 4];   // transposed A tile
  __shared__ float Bs[BK][BN + 4];
  const int tid  = threadIdx.x;
  const int tx   = tid & 15;         // cols tx*4
  const int ty   = tid >> 4;         // rows ty*4
  const int row0 = blockIdx.x * BM;

  float acc[TM][4] = {};

  const int ar     = tid >> 2;         // 0..63
  const int ac     = (tid & 3) * 8;
  const int bchunk = (tid & 15) * 4;   // 0..60
  const int brow0  = tid >> 4;         // 0..15

  for (int k0 = 0; k0 < K; k0 += BK) {
    // stage A (64x32) transposed
    {
      const int grow = row0 + ar;
      float4 t0, t1;
      if (grow < M) {
        const float* p = A + (size_t)grow * K + k0 + ac;
        t0 = *(const float4*)p;
        t1 = *(const float4*)(p + 4);
      } else {
        t0 = t1 = make_float4(0.f, 0.f, 0.f, 0.f);
      }
      As[ac + 0][ar] = t0.x; As[ac + 1][ar] = t0.y;
      As[ac + 2][ar] = t0.z; As[ac + 3][ar] = t0.w;
      As[ac + 4][ar] = t1.x; As[ac + 5][ar] = t1.y;
      As[ac + 6][ar] = t1.z; As[ac + 7][ar] = t1.w;
    }
    // stage B (32x64): 2 rounds
    #pragma unroll
    for (int q = 0; q < 2; ++q) {
      const int br = brow0 + 16 * q;
      *(float4*)&Bs[br][bchunk] =
          *(const float4*)(B + (size_t)(k0 + br) * BN + bchunk);
    }
    __syncthreads();

    #pragma unroll
    for (int kk = 0; kk < BK; ++kk) {
      const float4 a4 = *(const float4*)&As[kk][ty * TM];
      const float4 b4 = *(const float4*)&Bs[kk][tx * 4];
      const float a[4] = {a4.x, a4.y, a4.z, a4.w};
      const float b[4] = {b4.x, b4.y, b4.z, b4.w};
      #pragma unroll
      for (int i = 0; i < TM; ++i)
        #pragma unroll
        for (int j = 0; j < 4; ++j)
          acc[i][j] += a[i] * b[j];
    }
    __syncthreads();
  }

  const float4 u0 = *(const float4*)(bias + tx * 4);
  #pragma unroll
  for (int i = 0; i < TM; ++i) {
    const int grow = row0 + ty * TM + i;
    if (grow < M) {
      float4 r0 = make_float4(acc[i][0] + u0.x, acc[i][1] + u0.y,
                              acc[i][2] + u0.z, acc[i][3] + u0.w);
      *(float4*)(C + (size_t)grow * BN + tx * 4) = r0;
    }
  }
}

// ------------- Median over 32 neighbor rows (layer 1, D=128) + ReLU -------
// One wave per node, float2 per lane (64 lanes x 2 = 128 features).
// 4 nodes per 256-thread block.
__global__ __launch_bounds__(256) void median_relu1(const float* __restrict__ H,
                                                    const int* __restrict__ nb,
                                                    float* __restrict__ O) {
  const int node = blockIdx.x * 4 + (threadIdx.x >> 6);
  const int lane = threadIdx.x & 63;
  const float2* H2 = (const float2*)H;
  const int* nrow = nb + (size_t)node * KNB;
  float2 v[32];
  #pragma unroll
  for (int j = 0; j < KNB; ++j) {
    const int idx = nrow[j];
    v[j] = H2[(size_t)idx * 64 + lane];   // 8B/lane, full 512B row coalesced
  }
  sort32(v);
  const float2 m = v[15];
  ((float2*)O)[(size_t)node * 64 + lane] =
      make_float2(fmaxf(m.x, 0.f), fmaxf(m.y, 0.f));
}

// ------------- Median over 32 neighbor rows (layer 2, D=64) ---------------
// 32 lanes per node, float2 per lane; 8 nodes per 256-thread block.
__global__ __launch_bounds__(256) void median2(const float* __restrict__ H,
                                               const int* __restrict__ nb,
                                               float* __restrict__ O) {
  const int node = blockIdx.x * 8 + (threadIdx.x >> 5);
  const int lane = threadIdx.x & 31;
  const float2* H2 = (const float2*)H;
  const int* nrow = nb + (size_t)node * KNB;
  float2 v[32];
  #pragma unroll
  for (int j = 0; j < KNB; ++j) {
    const int idx = nrow[j];
    v[j] = H2[(size_t)idx * 32 + lane];   // 8B/lane, 256B row coalesced
  }
  sort32(v);
  ((float2*)O)[(size_t)node * 32 + lane] = v[15];
}

extern "C" void kernel_launch(void* const* d_in, const int* in_sizes, int n_in,
                              void* d_out, int out_size, void* d_ws, size_t ws_size,
                              hipStream_t stream) {
  const float* feat = (const float*)d_in[0];   // [50000,512]
  const float* W1   = (const float*)d_in[1];   // [512,128]
  const float* b1   = (const float*)d_in[2];   // [128]
  const float* W2   = (const float*)d_in[3];   // [128,64]
  const float* b2   = (const float*)d_in[4];   // [64]
  const int*   nb   = (const int*)d_in[5];     // [50000,32]
  float* out = (float*)d_out;                  // [50000,64]

  float* h1   = (float*)d_ws;                  // 25.6 MB
  float* med1 = h1 + (size_t)NN * 128;         // 25.6 MB
  float* h2   = h1;                            // reuse h1 region (dead)

  gemm1<<<dim3((NN + 63) / 64), dim3(256), 0, stream>>>(feat, W1, b1, h1, NN);
  median_relu1<<<dim3(NN / 4), dim3(256), 0, stream>>>(h1, nb, med1);
  gemm2<<<dim3((NN + 63) / 64), dim3(256), 0, stream>>>(med1, W2, b2, h2, NN);
  median2<<<dim3(NN / 8), dim3(256), 0, stream>>>(h2, nb, out);
}

// Round 4
// 308.653 us; speedup vs baseline: 1.3968x; 1.3968x over previous
//
#include <hip/hip_runtime.h>
#include <cstddef>

#define NN   50000
#define KNB  32

// Packed fp16 pair via clang vector extension (ROCm 7.2 lacks __hmin2/__hmax2
// in the __half API; __builtin_elementwise_min/max lower to v_pk_min/max_f16).
typedef _Float16 h2 __attribute__((ext_vector_type(2)));
typedef _Float16 h4 __attribute__((ext_vector_type(4)));

__device__ __forceinline__ void ceh(h2& a, h2& b) {
  h2 lo = __builtin_elementwise_min(a, b);
  h2 hi = __builtin_elementwise_max(a, b);
  a = lo;
  b = hi;
}

// Batcher odd-even mergesort, 32 elements (each an h2 = 2 independent
// feature lanes), fully unrolled. Only v[15] is consumed -> dead-cone DCE.
__device__ __forceinline__ void sort32h(h2 (&v)[32]) {
  #pragma unroll
  for (int p = 1; p < 32; p <<= 1) {
    #pragma unroll
    for (int k = p; k >= 1; k >>= 1) {
      #pragma unroll
      for (int j = k & (p - 1); j + k < 32; j += 2 * k) {
        #pragma unroll
        for (int i = 0; i < k; ++i) {
          if (i + j + k < 32) {
            if ((i + j) / (2 * p) == (i + j + k) / (2 * p)) {
              ceh(v[i + j], v[i + j + k]);
            }
          }
        }
      }
    }
  }
}

// ---------------- GEMM1: H1[M,128] = A[M,512] @ B[512,128] + bias ----------
// fp32 compute (no fp32 MFMA on CDNA4), fp16 output. 256 threads, BM=64,
// BN=128, TM=4, TN=8. As transposed [BK][BM+4]; Bs padded +4.
__global__ __launch_bounds__(256) void gemm1(const float* __restrict__ A,
                                             const float* __restrict__ B,
                                             const float* __restrict__ bias,
                                             _Float16* __restrict__ C, int M) {
  constexpr int K = 512, BM = 64, BN = 128, BK = 32, TM = 4;
  __shared__ float As[BK][BM + 4];
  __shared__ float Bs[BK][BN + 4];
  const int tid  = threadIdx.x;
  const int tx   = tid & 15;
  const int ty   = tid >> 4;
  const int row0 = blockIdx.x * BM;

  float acc[TM][8] = {};

  const int ar     = tid >> 2;
  const int ac     = (tid & 3) * 8;
  const int bchunk = (tid & 31) * 4;
  const int brow0  = tid >> 5;

  for (int k0 = 0; k0 < K; k0 += BK) {
    {
      const int grow = row0 + ar;
      float4 t0, t1;
      if (grow < M) {
        const float* p = A + (size_t)grow * K + k0 + ac;
        t0 = *(const float4*)p;
        t1 = *(const float4*)(p + 4);
      } else {
        t0 = t1 = make_float4(0.f, 0.f, 0.f, 0.f);
      }
      As[ac + 0][ar] = t0.x; As[ac + 1][ar] = t0.y;
      As[ac + 2][ar] = t0.z; As[ac + 3][ar] = t0.w;
      As[ac + 4][ar] = t1.x; As[ac + 5][ar] = t1.y;
      As[ac + 6][ar] = t1.z; As[ac + 7][ar] = t1.w;
    }
    #pragma unroll
    for (int q = 0; q < 4; ++q) {
      const int br = brow0 + 8 * q;
      *(float4*)&Bs[br][bchunk] =
          *(const float4*)(B + (size_t)(k0 + br) * BN + bchunk);
    }
    __syncthreads();

    #pragma unroll
    for (int kk = 0; kk < BK; ++kk) {
      const float4 a4 = *(const float4*)&As[kk][ty * TM];
      const float4 b0 = *(const float4*)&Bs[kk][tx * 4];
      const float4 b1 = *(const float4*)&Bs[kk][64 + tx * 4];
      const float a[4] = {a4.x, a4.y, a4.z, a4.w};
      const float b[8] = {b0.x, b0.y, b0.z, b0.w, b1.x, b1.y, b1.z, b1.w};
      #pragma unroll
      for (int i = 0; i < TM; ++i)
        #pragma unroll
        for (int j = 0; j < 8; ++j)
          acc[i][j] += a[i] * b[j];
    }
    __syncthreads();
  }

  const float4 u0 = *(const float4*)(bias + tx * 4);
  const float4 u1 = *(const float4*)(bias + 64 + tx * 4);
  #pragma unroll
  for (int i = 0; i < TM; ++i) {
    const int grow = row0 + ty * TM + i;
    if (grow < M) {
      h4 r0, r1;
      r0[0] = (_Float16)(acc[i][0] + u0.x);
      r0[1] = (_Float16)(acc[i][1] + u0.y);
      r0[2] = (_Float16)(acc[i][2] + u0.z);
      r0[3] = (_Float16)(acc[i][3] + u0.w);
      r1[0] = (_Float16)(acc[i][4] + u1.x);
      r1[1] = (_Float16)(acc[i][5] + u1.y);
      r1[2] = (_Float16)(acc[i][6] + u1.z);
      r1[3] = (_Float16)(acc[i][7] + u1.w);
      *(h4*)(C + (size_t)grow * BN + tx * 4)      = r0;
      *(h4*)(C + (size_t)grow * BN + 64 + tx * 4) = r1;
    }
  }
}

// ---------------- GEMM2: H2[M,64] = A[M,128](fp16) @ B[128,64] + bias -----
// fp16 input (widened to fp32 in staging), fp32 compute, fp16 output.
__global__ __launch_bounds__(256) void gemm2(const _Float16* __restrict__ A,
                                             const float* __restrict__ B,
                                             const float* __restrict__ bias,
                                             _Float16* __restrict__ C, int M) {
  constexpr int K = 128, BM = 64, BN = 64, BK = 32, TM = 4;
  __shared__ float As[BK][BM + 4];
  __shared__ float Bs[BK][BN + 4];
  const int tid  = threadIdx.x;
  const int tx   = tid & 15;
  const int ty   = tid >> 4;
  const int row0 = blockIdx.x * BM;

  float acc[TM][4] = {};

  const int ar     = tid >> 2;         // 0..63
  const int ac     = (tid & 3) * 8;    // k-offset, 8 halves = 16B
  const int bchunk = (tid & 15) * 4;
  const int brow0  = tid >> 4;

  for (int k0 = 0; k0 < K; k0 += BK) {
    {
      const int grow = row0 + ar;
      h2 h[4];
      if (grow < M) {
        *(float4*)h = *(const float4*)(A + (size_t)grow * K + k0 + ac);
      } else {
        h[0] = h[1] = h[2] = h[3] = (h2)((_Float16)0);
      }
      #pragma unroll
      for (int q = 0; q < 4; ++q) {
        As[ac + 2 * q + 0][ar] = (float)h[q][0];
        As[ac + 2 * q + 1][ar] = (float)h[q][1];
      }
    }
    #pragma unroll
    for (int q = 0; q < 2; ++q) {
      const int br = brow0 + 16 * q;
      *(float4*)&Bs[br][bchunk] =
          *(const float4*)(B + (size_t)(k0 + br) * BN + bchunk);
    }
    __syncthreads();

    #pragma unroll
    for (int kk = 0; kk < BK; ++kk) {
      const float4 a4 = *(const float4*)&As[kk][ty * TM];
      const float4 b4 = *(const float4*)&Bs[kk][tx * 4];
      const float a[4] = {a4.x, a4.y, a4.z, a4.w};
      const float b[4] = {b4.x, b4.y, b4.z, b4.w};
      #pragma unroll
      for (int i = 0; i < TM; ++i)
        #pragma unroll
        for (int j = 0; j < 4; ++j)
          acc[i][j] += a[i] * b[j];
    }
    __syncthreads();
  }

  const float4 u0 = *(const float4*)(bias + tx * 4);
  #pragma unroll
  for (int i = 0; i < TM; ++i) {
    const int grow = row0 + ty * TM + i;
    if (grow < M) {
      h4 r;
      r[0] = (_Float16)(acc[i][0] + u0.x);
      r[1] = (_Float16)(acc[i][1] + u0.y);
      r[2] = (_Float16)(acc[i][2] + u0.z);
      r[3] = (_Float16)(acc[i][3] + u0.w);
      *(h4*)(C + (size_t)grow * BN + tx * 4) = r;
    }
  }
}

// ------------- Median over 32 neighbor rows (layer 1, D=128) + ReLU -------
// One wave per node; lane holds h2 (64 lanes x 2 = 128 features). Gather is
// 4B/lane = 256B/row per wave (coalesced). Packed fp16 sorting network.
__global__ __launch_bounds__(256) void median_relu1(const h2* __restrict__ H,
                                                    const int* __restrict__ nb,
                                                    h2* __restrict__ O) {
  const int node = blockIdx.x * 4 + (threadIdx.x >> 6);
  const int lane = threadIdx.x & 63;
  const int* nrow = nb + (size_t)node * KNB;
  h2 v[32];
  #pragma unroll
  for (int j = 0; j < KNB; ++j) {
    const int idx = nrow[j];
    v[j] = H[(size_t)idx * 64 + lane];
  }
  sort32h(v);
  const h2 z = (h2)((_Float16)0);
  O[(size_t)node * 64 + lane] = __builtin_elementwise_max(v[15], z);
}

// ------------- Median over 32 neighbor rows (layer 2, D=64) ---------------
// 32 lanes per node, h2 per lane; fp32 output (d_out dtype).
__global__ __launch_bounds__(256) void median2(const h2* __restrict__ H,
                                               const int* __restrict__ nb,
                                               float2* __restrict__ O) {
  const int node = blockIdx.x * 8 + (threadIdx.x >> 5);
  const int lane = threadIdx.x & 31;
  const int* nrow = nb + (size_t)node * KNB;
  h2 v[32];
  #pragma unroll
  for (int j = 0; j < KNB; ++j) {
    const int idx = nrow[j];
    v[j] = H[(size_t)idx * 32 + lane];
  }
  sort32h(v);
  float2 o;
  o.x = (float)v[15][0];
  o.y = (float)v[15][1];
  O[(size_t)node * 32 + lane] = o;
}

extern "C" void kernel_launch(void* const* d_in, const int* in_sizes, int n_in,
                              void* d_out, int out_size, void* d_ws, size_t ws_size,
                              hipStream_t stream) {
  const float* feat = (const float*)d_in[0];   // [50000,512]
  const float* W1   = (const float*)d_in[1];   // [512,128]
  const float* b1   = (const float*)d_in[2];   // [128]
  const float* W2   = (const float*)d_in[3];   // [128,64]
  const float* b2   = (const float*)d_in[4];   // [64]
  const int*   nb   = (const int*)d_in[5];     // [50000,32]
  float* out = (float*)d_out;                  // [50000,64] fp32

  _Float16* h1   = (_Float16*)d_ws;                   // 12.8 MB
  _Float16* med1 = h1 + (size_t)NN * 128;             // 12.8 MB
  _Float16* h2buf = h1;                               // reuse (h1 dead)

  gemm1<<<dim3((NN + 63) / 64), dim3(256), 0, stream>>>(feat, W1, b1, h1, NN);
  median_relu1<<<dim3(NN / 4), dim3(256), 0, stream>>>(
      (const h2*)h1, nb, (h2*)med1);
  gemm2<<<dim3((NN + 63) / 64), dim3(256), 0, stream>>>(med1, W2, b2, h2buf, NN);
  median2<<<dim3(NN / 8), dim3(256), 0, stream>>>(
      (const h2*)h2buf, nb, (float2*)out);
}

// Round 5
// 299.673 us; speedup vs baseline: 1.4386x; 1.0300x over previous
//
#include <hip/hip_runtime.h>
#include <cstddef>

#define NN   50000
#define KNB  32

typedef _Float16 h2    __attribute__((ext_vector_type(2)));
typedef _Float16 half8 __attribute__((ext_vector_type(8)));
typedef float    f4    __attribute__((ext_vector_type(4)));
typedef float    f8    __attribute__((ext_vector_type(8)));

// ---------------- prep: W1^T and W2^T as fp16 [N][K] ----------------------
// W is tiny (W1 64K elems, W2 8K). One-off transpose+cast so the GEMMs can
// read B-fragments (8 contiguous k per lane) with a single 16B load.
__global__ __launch_bounds__(256) void prep(const float* __restrict__ W1,
                                            const float* __restrict__ W2,
                                            _Float16* __restrict__ w1t,
                                            _Float16* __restrict__ w2t) {
  const int id = blockIdx.x * 256 + threadIdx.x;
  if (id < 128 * 512) {                     // w1t[n][k] = W1[k][n]
    const int n = id >> 9, k = id & 511;
    w1t[id] = (_Float16)W1[k * 128 + n];
  } else {
    const int id2 = id - 128 * 512;
    if (id2 < 64 * 128) {                   // w2t[n][k] = W2[k][n]
      const int n = id2 >> 7, k = id2 & 127;
      w2t[id2] = (_Float16)W2[k * 64 + n];
    }
  }
}

// ---------------- GEMM1: H1[M,128] = A[M,512]fp32 @ W1 + b1, fp16 out -----
// MFMA f32_16x16x32_f16, fp32 accumulate. No LDS, no barriers: A-fragments
// loaded straight from global (fp32 -> fp16 in-register); B-fragments from
// w1t (128 KB, L2-resident, shared by all blocks). Wave = 16 rows x 128 cols
// (8 tiles); block = 4 waves = 64 rows. Fragment layouts (verified, guide §3):
//   A: m=lane&15, k=(lane>>4)*8+j   B(=W^T row): n=lane&15, k=(lane>>4)*8+j
//   C/D: col=lane&15, row=(lane>>4)*4+reg
__global__ __launch_bounds__(256) void gemm1_mfma(
    const float* __restrict__ A, const _Float16* __restrict__ Bt,
    const float* __restrict__ bias, _Float16* __restrict__ C, int M) {
  constexpr int K = 512;
  const int wave = threadIdx.x >> 6;
  const int lane = threadIdx.x & 63;
  const int m0   = blockIdx.x * 64 + wave * 16;
  const int mr   = lane & 15;
  const int kg   = lane >> 4;

  int arow = m0 + mr;
  if (arow >= M) arow = M - 1;               // clamp: garbage rows discarded at store
  const float*    ap = A  + (size_t)arow * K + kg * 8;
  const _Float16* bp = Bt + (size_t)mr   * K + kg * 8;

  f4 acc[8] = {};

  #pragma unroll 2
  for (int k0 = 0; k0 < K; k0 += 32) {
    const f4 a0 = *(const f4*)ap;
    const f4 a1 = *(const f4*)(ap + 4);
    const f8 av = {a0[0], a0[1], a0[2], a0[3], a1[0], a1[1], a1[2], a1[3]};
    const half8 af = __builtin_convertvector(av, half8);
    #pragma unroll
    for (int nt = 0; nt < 8; ++nt) {
      const half8 bf = *(const half8*)(bp + (size_t)nt * 16 * K);
      acc[nt] = __builtin_amdgcn_mfma_f32_16x16x32_f16(af, bf, acc[nt], 0, 0, 0);
    }
    ap += 32;
    bp += 32;
  }

  #pragma unroll
  for (int nt = 0; nt < 8; ++nt) {
    const int col = nt * 16 + mr;
    const float bv = bias[col];
    #pragma unroll
    for (int r = 0; r < 4; ++r) {
      const int row = m0 + kg * 4 + r;
      if (row < M)
        C[(size_t)row * 128 + col] = (_Float16)(acc[nt][r] + bv);
    }
  }
}

// ---------------- GEMM2: H2[M,64] = A[M,128]fp16 @ W2 + b2, fp16 out ------
// Same structure; A is already fp16 -> fragment is one 16B load.
__global__ __launch_bounds__(256) void gemm2_mfma(
    const _Float16* __restrict__ A, const _Float16* __restrict__ Bt,
    const float* __restrict__ bias, _Float16* __restrict__ C, int M) {
  constexpr int K = 128;
  const int wave = threadIdx.x >> 6;
  const int lane = threadIdx.x & 63;
  const int m0   = blockIdx.x * 64 + wave * 16;
  const int mr   = lane & 15;
  const int kg   = lane >> 4;

  int arow = m0 + mr;
  if (arow >= M) arow = M - 1;
  const _Float16* ap = A  + (size_t)arow * K + kg * 8;
  const _Float16* bp = Bt + (size_t)mr   * K + kg * 8;

  f4 acc[4] = {};

  #pragma unroll
  for (int k0 = 0; k0 < K; k0 += 32) {
    const half8 af = *(const half8*)ap;
    #pragma unroll
    for (int nt = 0; nt < 4; ++nt) {
      const half8 bf = *(const half8*)(bp + (size_t)nt * 16 * K);
      acc[nt] = __builtin_amdgcn_mfma_f32_16x16x32_f16(af, bf, acc[nt], 0, 0, 0);
    }
    ap += 32;
    bp += 32;
  }

  #pragma unroll
  for (int nt = 0; nt < 4; ++nt) {
    const int col = nt * 16 + mr;
    const float bv = bias[col];
    #pragma unroll
    for (int r = 0; r < 4; ++r) {
      const int row = m0 + kg * 4 + r;
      if (row < M)
        C[(size_t)row * 64 + col] = (_Float16)(acc[nt][r] + bv);
    }
  }
}

// ---------------- median machinery (unchanged from R4) --------------------
__device__ __forceinline__ void ceh(h2& a, h2& b) {
  h2 lo = __builtin_elementwise_min(a, b);
  h2 hi = __builtin_elementwise_max(a, b);
  a = lo;
  b = hi;
}

// Batcher odd-even mergesort, 32 h2 elements; only v[15] consumed -> DCE.
__device__ __forceinline__ void sort32h(h2 (&v)[32]) {
  #pragma unroll
  for (int p = 1; p < 32; p <<= 1) {
    #pragma unroll
    for (int k = p; k >= 1; k >>= 1) {
      #pragma unroll
      for (int j = k & (p - 1); j + k < 32; j += 2 * k) {
        #pragma unroll
        for (int i = 0; i < k; ++i) {
          if (i + j + k < 32) {
            if ((i + j) / (2 * p) == (i + j + k) / (2 * p)) {
              ceh(v[i + j], v[i + j + k]);
            }
          }
        }
      }
    }
  }
}

// Median over 32 neighbor rows (layer 1, D=128) + ReLU. One wave per node.
__global__ __launch_bounds__(256) void median_relu1(const h2* __restrict__ H,
                                                    const int* __restrict__ nb,
                                                    h2* __restrict__ O) {
  const int node = blockIdx.x * 4 + (threadIdx.x >> 6);
  const int lane = threadIdx.x & 63;
  const int* nrow = nb + (size_t)node * KNB;
  h2 v[32];
  #pragma unroll
  for (int j = 0; j < KNB; ++j) {
    const int idx = nrow[j];
    v[j] = H[(size_t)idx * 64 + lane];
  }
  sort32h(v);
  const h2 z = (h2)((_Float16)0);
  O[(size_t)node * 64 + lane] = __builtin_elementwise_max(v[15], z);
}

// Median over 32 neighbor rows (layer 2, D=64); fp32 output.
__global__ __launch_bounds__(256) void median2(const h2* __restrict__ H,
                                               const int* __restrict__ nb,
                                               float2* __restrict__ O) {
  const int node = blockIdx.x * 8 + (threadIdx.x >> 5);
  const int lane = threadIdx.x & 31;
  const int* nrow = nb + (size_t)node * KNB;
  h2 v[32];
  #pragma unroll
  for (int j = 0; j < KNB; ++j) {
    const int idx = nrow[j];
    v[j] = H[(size_t)idx * 32 + lane];
  }
  sort32h(v);
  float2 o;
  o.x = (float)v[15][0];
  o.y = (float)v[15][1];
  O[(size_t)node * 32 + lane] = o;
}

extern "C" void kernel_launch(void* const* d_in, const int* in_sizes, int n_in,
                              void* d_out, int out_size, void* d_ws, size_t ws_size,
                              hipStream_t stream) {
  const float* feat = (const float*)d_in[0];   // [50000,512]
  const float* W1   = (const float*)d_in[1];   // [512,128]
  const float* b1   = (const float*)d_in[2];   // [128]
  const float* W2   = (const float*)d_in[3];   // [128,64]
  const float* b2   = (const float*)d_in[4];   // [64]
  const int*   nb   = (const int*)d_in[5];     // [50000,32]
  float* out = (float*)d_out;                  // [50000,64] fp32

  _Float16* h1   = (_Float16*)d_ws;                 // 12.8 MB
  _Float16* med1 = h1 + (size_t)NN * 128;           // 12.8 MB
  _Float16* w1t  = med1 + (size_t)NN * 128;         // 128 KB  [128][512]
  _Float16* w2t  = w1t + 128 * 512;                 // 16 KB   [64][128]
  _Float16* h2b  = h1;                              // reuse (h1 dead)

  prep<<<dim3(288), dim3(256), 0, stream>>>(W1, W2, w1t, w2t);
  gemm1_mfma<<<dim3((NN + 63) / 64), dim3(256), 0, stream>>>(feat, w1t, b1, h1, NN);
  median_relu1<<<dim3(NN / 4), dim3(256), 0, stream>>>(
      (const h2*)h1, nb, (h2*)med1);
  gemm2_mfma<<<dim3((NN + 63) / 64), dim3(256), 0, stream>>>(med1, w2t, b2, h2b, NN);
  median2<<<dim3(NN / 8), dim3(256), 0, stream>>>(
      (const h2*)h2b, nb, (float2*)out);
}